// Round 12
// baseline (565.948 us; speedup 1.0000x reference)
//
#include <hip/hip_runtime.h>

#define N_NODES 100000
#define N_EDGES 1600000
#define HID 128
#define LAT 64
#define N_LAYERS 3
#define N_GRAPHS 1000
#define CAP 64                                    // slots per node (P(deg>=64)~1e-19)
#define NBIN 391                                  // dst bins of 256 nodes (d >> 8)
#define MAXBIN 4608                               // bin capacity: mean 4096 + 8*sigma
#define ACHUNK 8192
#define ABLOCKS ((N_EDGES + ACHUNK - 1) / ACHUNK) // 196

typedef short bf16x8 __attribute__((ext_vector_type(8)));
typedef float f32x4 __attribute__((ext_vector_type(4)));

__device__ __forceinline__ float bf2f(unsigned short h) {
    union { unsigned int u; float f; } c;
    c.u = ((unsigned int)h) << 16;
    return c.f;
}
__device__ __forceinline__ unsigned short f2bf(float f) {
    union { float f; unsigned int u; } c;
    c.f = f;
    unsigned int u = c.u;
    return (unsigned short)((u + 0x7fffu + ((u >> 16) & 1u)) >> 16);
}
__device__ __forceinline__ unsigned int pack2(float a, float b) {
    return (unsigned int)f2bf(a) | ((unsigned int)f2bf(b) << 16);
}
__device__ __forceinline__ void addrow(float* acc, uint4 w) {
    acc[0] += bf2f((unsigned short)w.x); acc[1] += bf2f((unsigned short)(w.x >> 16));
    acc[2] += bf2f((unsigned short)w.y); acc[3] += bf2f((unsigned short)(w.y >> 16));
    acc[4] += bf2f((unsigned short)w.z); acc[5] += bf2f((unsigned short)(w.z >> 16));
    acc[6] += bf2f((unsigned short)w.w); acc[7] += bf2f((unsigned short)(w.w >> 16));
}

// ---------------- convert x fp32 -> bf16 ----------------
__global__ __launch_bounds__(256) void cvt_x_kernel(const float* __restrict__ x,
                                                    unsigned short* __restrict__ xb, int n4) {
    int i = blockIdx.x * 256 + threadIdx.x;
    if (i >= n4) return;
    float4 v = ((const float4*)x)[i];
    ((uint2*)xb)[i] = make_uint2(pack2(v.x, v.y), pack2(v.z, v.w));
}

// ---------------- W [k][n] fp32 -> Wt [n][k] bf16, 6 matrices ----------------
__global__ __launch_bounds__(256) void wt_kernel(const float* __restrict__ W1,
                                                 const float* __restrict__ W2,
                                                 unsigned short* __restrict__ Wt) {
    int m = blockIdx.x;  // 0..5 : layer*2 + phase
    const float* W = ((m & 1) ? W2 : W1) + (size_t)(m >> 1) * HID * HID;
    unsigned short* D = Wt + (size_t)m * HID * HID;
    for (int idx = threadIdx.x; idx < HID * HID; idx += 256) {
        int n = idx >> 7, k = idx & 127;
        D[n * HID + k] = f2bf(W[k * HID + n]);
    }
}

// ---------------- binA: edges -> per-bin dense runs, packed (dlocal<<24)|src ----------------
__global__ __launch_bounds__(256) void binA_kernel(const int* __restrict__ ei,
                                                   int* __restrict__ gcnt,
                                                   unsigned int* __restrict__ ebin) {
    __shared__ unsigned int scount[NBIN];
    __shared__ unsigned int sfill[NBIN];
    int t = threadIdx.x;
    int base = blockIdx.x * ACHUNK;
    int n = N_EDGES - base;
    if (n > ACHUNK) n = ACHUNK;
    for (int i = t; i < NBIN; i += 256) scount[i] = 0u;
    __syncthreads();
    for (int i = t; i < n; i += 256) {
        int d = ei[N_EDGES + base + i];
        atomicAdd(&scount[d >> 8], 1u);
    }
    __syncthreads();
    for (int b = t; b < NBIN; b += 256) {
        unsigned int c = scount[b];
        sfill[b] = c ? (unsigned int)atomicAdd(&gcnt[b], (int)c) : 0u;
    }
    __syncthreads();
    for (int i = t; i < n; i += 256) {
        int s = ei[base + i];
        int d = ei[N_EDGES + base + i];
        int b = d >> 8;
        unsigned int pos = atomicAdd(&sfill[b], 1u);
        ebin[(size_t)b * MAXBIN + pos] = ((unsigned int)(d & 255) << 24) | (unsigned int)s;
    }
}

// ---------------- binB: drain bin -> slot csr, all block-local ----------------
__global__ __launch_bounds__(256) void binB_kernel(const unsigned int* __restrict__ ebin,
                                                   const int* __restrict__ gcnt,
                                                   int* __restrict__ cnt,
                                                   int* __restrict__ csr) {
    __shared__ int scnt[256];
    int b = blockIdx.x;
    int t = threadIdx.x;
    scnt[t] = 0;
    __syncthreads();
    int n0 = b << 8;
    int c = gcnt[b];
    const unsigned int* src = ebin + (size_t)b * MAXBIN;
    for (int i = t; i < c; i += 256) {
        unsigned int e = src[i];
        int dl = (int)(e >> 24);
        int slot = atomicAdd(&scnt[dl], 1);
        csr[(size_t)(n0 + dl) * CAP + slot] = (int)(e & 0xFFFFFFu);
    }
    __syncthreads();
    int node = n0 + t;
    if (node < N_NODES) cnt[node] = scnt[t];
}

// ---------------- gather (bf16): agg[n] = h[n] + sum_{s in N(n)} h[s] ----------------
__global__ __launch_bounds__(256) void gather_kernel(const unsigned short* __restrict__ h,
                                                     const int* __restrict__ cnt,
                                                     const int* __restrict__ csr,
                                                     unsigned short* __restrict__ agg) {
    int t = threadIdx.x;
    int node = blockIdx.x * 16 + (t >> 4);
    int q = t & 15;
    if (node >= N_NODES) return;
    const int* nl = csr + (size_t)node * CAP;
    int deg = cnt[node];
    float acc[8] = {0.f, 0.f, 0.f, 0.f, 0.f, 0.f, 0.f, 0.f};
    addrow(acc, *(const uint4*)(h + (size_t)node * HID + q * 8));
    int e = 0;
    for (; e + 8 <= deg; e += 8) {
        int s0 = nl[e], s1 = nl[e + 1], s2 = nl[e + 2], s3 = nl[e + 3];
        int s4 = nl[e + 4], s5 = nl[e + 5], s6 = nl[e + 6], s7 = nl[e + 7];
        uint4 w0 = *(const uint4*)(h + (size_t)s0 * HID + q * 8);
        uint4 w1 = *(const uint4*)(h + (size_t)s1 * HID + q * 8);
        uint4 w2 = *(const uint4*)(h + (size_t)s2 * HID + q * 8);
        uint4 w3 = *(const uint4*)(h + (size_t)s3 * HID + q * 8);
        uint4 w4 = *(const uint4*)(h + (size_t)s4 * HID + q * 8);
        uint4 w5 = *(const uint4*)(h + (size_t)s5 * HID + q * 8);
        uint4 w6 = *(const uint4*)(h + (size_t)s6 * HID + q * 8);
        uint4 w7 = *(const uint4*)(h + (size_t)s7 * HID + q * 8);
        addrow(acc, w0); addrow(acc, w1); addrow(acc, w2); addrow(acc, w3);
        addrow(acc, w4); addrow(acc, w5); addrow(acc, w6); addrow(acc, w7);
    }
    for (; e + 4 <= deg; e += 4) {
        int s0 = nl[e], s1 = nl[e + 1], s2 = nl[e + 2], s3 = nl[e + 3];
        uint4 w0 = *(const uint4*)(h + (size_t)s0 * HID + q * 8);
        uint4 w1 = *(const uint4*)(h + (size_t)s1 * HID + q * 8);
        uint4 w2 = *(const uint4*)(h + (size_t)s2 * HID + q * 8);
        uint4 w3 = *(const uint4*)(h + (size_t)s3 * HID + q * 8);
        addrow(acc, w0); addrow(acc, w1); addrow(acc, w2); addrow(acc, w3);
    }
    for (; e < deg; ++e) {
        addrow(acc, *(const uint4*)(h + (size_t)nl[e] * HID + q * 8));
    }
    uint4 o;
    o.x = pack2(acc[0], acc[1]);
    o.y = pack2(acc[2], acc[3]);
    o.z = pack2(acc[4], acc[5]);
    o.w = pack2(acc[6], acc[7]);
    *(uint4*)(agg + (size_t)node * HID + q * 8) = o;
}

// ---------------- MFMA MLP, barrier-light: fragments direct from global ----------------
// 4 waves, 16 rows/wave. a_frag A[m=lane&15][k=quad*8+j] read straight from
// global (wave touches a contiguous 4KB region -> line-covered); b_frag from
// Wt[n][k] (L2-resident 32KB). H1 hand-off is WAVE-LOCAL via sH[w] (phase-1
// epilogue rows == phase-2 input rows for the same wave) -> no barrier.
// Only 1 __syncthreads (before the cross-wave cooperative store).
__global__ __launch_bounds__(256) void mlp_kernel(const unsigned short* __restrict__ A,
                                                  const unsigned short* __restrict__ W1t,
                                                  const float* __restrict__ b1,
                                                  const unsigned short* __restrict__ W2t,
                                                  const float* __restrict__ b2,
                                                  unsigned short* __restrict__ out) {
    __shared__ unsigned short sH[4][16][136];  // per-wave H1/out tile, row stride 272B
    const int t = threadIdx.x;
    const int w = t >> 6;
    const int l = t & 63;
    const int lm = l & 15;
    const int quad = l >> 4;
    const int row0 = blockIdx.x * 64 + w * 16;

    // ---- phase 1: H1 = relu(A@W1 + b1) ----
    int arow = row0 + lm;
    if (arow >= N_NODES) arow = N_NODES - 1;  // clamp: loads only, never stored
    const unsigned short* Arow = A + (size_t)arow * HID;
    f32x4 acc[8];
#pragma unroll
    for (int nt = 0; nt < 8; ++nt) acc[nt] = (f32x4){0.f, 0.f, 0.f, 0.f};
#pragma unroll
    for (int kc = 0; kc < 4; ++kc) {
        bf16x8 a = *(const bf16x8*)(Arow + kc * 32 + quad * 8);
#pragma unroll
        for (int nt = 0; nt < 8; ++nt) {
            bf16x8 b = *(const bf16x8*)(W1t + (size_t)(nt * 16 + lm) * HID + kc * 32 + quad * 8);
            acc[nt] = __builtin_amdgcn_mfma_f32_16x16x32_bf16(a, b, acc[nt], 0, 0, 0);
        }
    }
#pragma unroll
    for (int nt = 0; nt < 8; ++nt) {
        float bv = b1[nt * 16 + lm];
#pragma unroll
        for (int r = 0; r < 4; ++r) {
            sH[w][quad * 4 + r][nt * 16 + lm] = f2bf(fmaxf(acc[nt][r] + bv, 0.f));
        }
    }
    // wave-local hand-off: same wave wrote all 16 rows it now reads (lockstep
    // wave + compiler lgkmcnt ordering) -> no __syncthreads needed.

    // ---- phase 2: out = relu(H1@W2 + b2) ----
    f32x4 acc2[8];
#pragma unroll
    for (int nt = 0; nt < 8; ++nt) acc2[nt] = (f32x4){0.f, 0.f, 0.f, 0.f};
#pragma unroll
    for (int kc = 0; kc < 4; ++kc) {
        bf16x8 a = *(const bf16x8*)&sH[w][lm][kc * 32 + quad * 8];
#pragma unroll
        for (int nt = 0; nt < 8; ++nt) {
            bf16x8 b = *(const bf16x8*)(W2t + (size_t)(nt * 16 + lm) * HID + kc * 32 + quad * 8);
            acc2[nt] = __builtin_amdgcn_mfma_f32_16x16x32_bf16(a, b, acc2[nt], 0, 0, 0);
        }
    }
#pragma unroll
    for (int nt = 0; nt < 8; ++nt) {
        float bv = b2[nt * 16 + lm];
#pragma unroll
        for (int r = 0; r < 4; ++r) {
            sH[w][quad * 4 + r][nt * 16 + lm] = f2bf(fmaxf(acc2[nt][r] + bv, 0.f));
        }
    }
    __syncthreads();  // cross-wave cooperative store below
    for (int idx = t; idx < 1024; idx += 256) {
        int r = idx >> 4, c = idx & 15;
        int grow = blockIdx.x * 64 + r;
        if (grow < N_NODES)
            *(uint4*)(out + (size_t)grow * HID + c * 8) = *(const uint4*)&sH[r >> 4][r & 15][c * 8];
    }
}

// ---------------- pool (round-9 proven) ----------------
__global__ __launch_bounds__(256) void pool_kernel(const unsigned short* __restrict__ h,
                                                   const int* __restrict__ batch,
                                                   float* __restrict__ g) {
    const int S = 16;  // nodes per 16-lane group
    int t = threadIdx.x;
    int grp = t >> 4;
    int q = t & 15;
    int n0 = (blockIdx.x * 16 + grp) * S;
    if (n0 >= N_NODES) return;
    int n1 = n0 + S;
    if (n1 > N_NODES) n1 = N_NODES;
    int cur = batch[n0];
    float acc[8] = {0.f, 0.f, 0.f, 0.f, 0.f, 0.f, 0.f, 0.f};
    for (int n = n0; n < n1; ++n) {
        int b = batch[n];
        if (b != cur) {
            float* gp = g + (size_t)cur * HID + q * 8;
#pragma unroll
            for (int i = 0; i < 8; ++i) { atomicAdd(gp + i, acc[i]); acc[i] = 0.f; }
            cur = b;
        }
        addrow(acc, *(const uint4*)(h + (size_t)n * HID + q * 8));
    }
    float* gp = g + (size_t)cur * HID + q * 8;
#pragma unroll
    for (int i = 0; i < 8; ++i) atomicAdd(gp + i, acc[i]);
}

// ---------------- heads ----------------
__global__ __launch_bounds__(128) void head_kernel(const float* __restrict__ g,
                                                   const float* __restrict__ Wmu,
                                                   const float* __restrict__ bmu,
                                                   const float* __restrict__ Wlv,
                                                   const float* __restrict__ blv,
                                                   float* __restrict__ out) {
    __shared__ float sg[HID];
    int gi = blockIdx.x;
    sg[threadIdx.x] = g[(size_t)gi * HID + threadIdx.x];
    __syncthreads();
    int j = threadIdx.x & 63;
    bool is_lv = threadIdx.x >= 64;
    const float* W = is_lv ? Wlv : Wmu;
    float acc = is_lv ? blv[j] : bmu[j];
    for (int k = 0; k < HID; ++k) acc = fmaf(sg[k], W[k * LAT + j], acc);
    out[(is_lv ? (size_t)N_GRAPHS * LAT : 0) + (size_t)gi * LAT + j] = acc;
}

extern "C" void kernel_launch(void* const* d_in, const int* in_sizes, int n_in,
                              void* d_out, int out_size, void* d_ws, size_t ws_size,
                              hipStream_t stream) {
    const float* x     = (const float*)d_in[0];
    const int*   ei    = (const int*)d_in[1];
    const int*   batch = (const int*)d_in[2];
    const float* W1    = (const float*)d_in[3];
    const float* b1    = (const float*)d_in[4];
    const float* W2    = (const float*)d_in[5];
    const float* b2    = (const float*)d_in[6];
    const float* Wmu   = (const float*)d_in[7];
    const float* bmu   = (const float*)d_in[8];
    const float* Wlv   = (const float*)d_in[9];
    const float* blv   = (const float*)d_in[10];
    float* out = (float*)d_out;

    float* g = (float*)d_ws;                                       // 512 KB
    unsigned short* xb   = (unsigned short*)(g + (size_t)N_GRAPHS * HID);
    unsigned short* agg  = xb + (size_t)N_NODES * HID;             // 25.6 MB each
    unsigned short* hbuf = agg + (size_t)N_NODES * HID;
    unsigned short* Wt   = hbuf + (size_t)N_NODES * HID;           // 192 KB
    int* cnt  = (int*)(Wt + (size_t)6 * HID * HID);                // 400 KB
    int* gcnt = cnt + N_NODES;                                     // 1.6 KB
    int* csr  = gcnt + NBIN + 1;                                   // 25.6 MB
    unsigned int* ebin = (unsigned int*)(csr + (size_t)N_NODES * CAP);  // 7.2 MB

    // ---- CSR build: LDS-binned two-phase ----
    hipMemsetAsync(gcnt, 0, (size_t)NBIN * sizeof(int), stream);
    binA_kernel<<<ABLOCKS, 256, 0, stream>>>(ei, gcnt, ebin);
    binB_kernel<<<NBIN, 256, 0, stream>>>(ebin, gcnt, cnt, csr);

    // ---- prep bf16 ----
    cvt_x_kernel<<<(N_NODES * HID / 4 + 255) / 256, 256, 0, stream>>>(x, xb,
                                                                      N_NODES * HID / 4);
    wt_kernel<<<6, 256, 0, stream>>>(W1, W2, Wt);

    const unsigned short* hcur = xb;
    for (int i = 0; i < N_LAYERS; ++i) {
        gather_kernel<<<(N_NODES + 15) / 16, 256, 0, stream>>>(hcur, cnt, csr, agg);
        mlp_kernel<<<(N_NODES + 63) / 64, 256, 0, stream>>>(
            agg, Wt + (size_t)(2 * i) * HID * HID, b1 + (size_t)i * HID,
            Wt + (size_t)(2 * i + 1) * HID * HID, b2 + (size_t)i * HID, hbuf);
        hcur = hbuf;
    }
    hipMemsetAsync(g, 0, (size_t)N_GRAPHS * HID * sizeof(float), stream);
    pool_kernel<<<(N_NODES + 255) / 256, 256, 0, stream>>>(hcur, batch, g);
    head_kernel<<<N_GRAPHS, 128, 0, stream>>>(g, Wmu, bmu, Wlv, blv, out);
}

// Round 13
// 490.807 us; speedup vs baseline: 1.1531x; 1.1531x over previous
//
#include <hip/hip_runtime.h>

#define N_NODES 100000
#define N_EDGES 1600000
#define HID 128
#define LAT 64
#define N_LAYERS 3
#define N_GRAPHS 1000
#define CAP 64                                    // slots per node (P(deg>=64)~1e-19)
#define NBIN 391                                  // dst bins of 256 nodes (d >> 8)
#define MAXBIN 4608                               // bin capacity: mean 4096 + 8*sigma
#define ACHUNK 8192
#define ABLOCKS ((N_EDGES + ACHUNK - 1) / ACHUNK) // 196
#define CVT_BLOCKS (N_NODES * HID / 4 / 256)      // 12500

typedef short bf16x8 __attribute__((ext_vector_type(8)));
typedef float f32x4 __attribute__((ext_vector_type(4)));

__device__ __forceinline__ float bf2f(unsigned short h) {
    union { unsigned int u; float f; } c;
    c.u = ((unsigned int)h) << 16;
    return c.f;
}
__device__ __forceinline__ unsigned short f2bf(float f) {
    union { float f; unsigned int u; } c;
    c.f = f;
    unsigned int u = c.u;
    return (unsigned short)((u + 0x7fffu + ((u >> 16) & 1u)) >> 16);
}
__device__ __forceinline__ unsigned int pack2(float a, float b) {
    return (unsigned int)f2bf(a) | ((unsigned int)f2bf(b) << 16);
}
__device__ __forceinline__ void addrow(float* acc, uint4 w) {
    acc[0] += bf2f((unsigned short)w.x); acc[1] += bf2f((unsigned short)(w.x >> 16));
    acc[2] += bf2f((unsigned short)w.y); acc[3] += bf2f((unsigned short)(w.y >> 16));
    acc[4] += bf2f((unsigned short)w.z); acc[5] += bf2f((unsigned short)(w.z >> 16));
    acc[6] += bf2f((unsigned short)w.w); acc[7] += bf2f((unsigned short)(w.w >> 16));
}

// ---------------- prep: fused x fp32->bf16 + W transpose->bf16 ----------------
__global__ __launch_bounds__(256) void prep_kernel(const float* __restrict__ x,
                                                   unsigned short* __restrict__ xb,
                                                   const float* __restrict__ W1,
                                                   const float* __restrict__ W2,
                                                   unsigned short* __restrict__ Wt) {
    int blk = blockIdx.x;
    if (blk < 6) {
        const float* W = ((blk & 1) ? W2 : W1) + (size_t)(blk >> 1) * HID * HID;
        unsigned short* D = Wt + (size_t)blk * HID * HID;
        for (int idx = threadIdx.x; idx < HID * HID; idx += 256) {
            int n = idx >> 7, k = idx & 127;
            D[n * HID + k] = f2bf(W[k * HID + n]);
        }
        return;
    }
    int i = (blk - 6) * 256 + threadIdx.x;
    if (i >= N_NODES * HID / 4) return;
    float4 v = ((const float4*)x)[i];
    ((uint2*)xb)[i] = make_uint2(pack2(v.x, v.y), pack2(v.z, v.w));
}

// ---------------- binA: edges -> per-bin dense runs, packed (dlocal<<24)|src ----------------
__global__ __launch_bounds__(256) void binA_kernel(const int* __restrict__ ei,
                                                   int* __restrict__ gcnt,
                                                   unsigned int* __restrict__ ebin) {
    __shared__ unsigned int scount[NBIN];
    __shared__ unsigned int sfill[NBIN];
    int t = threadIdx.x;
    int base = blockIdx.x * ACHUNK;
    int n = N_EDGES - base;
    if (n > ACHUNK) n = ACHUNK;
    for (int i = t; i < NBIN; i += 256) scount[i] = 0u;
    __syncthreads();
    for (int i = t; i < n; i += 256) {
        int d = ei[N_EDGES + base + i];
        atomicAdd(&scount[d >> 8], 1u);
    }
    __syncthreads();
    for (int b = t; b < NBIN; b += 256) {
        unsigned int c = scount[b];
        sfill[b] = c ? (unsigned int)atomicAdd(&gcnt[b], (int)c) : 0u;
    }
    __syncthreads();
    for (int i = t; i < n; i += 256) {
        int s = ei[base + i];
        int d = ei[N_EDGES + base + i];
        int b = d >> 8;
        unsigned int pos = atomicAdd(&sfill[b], 1u);
        ebin[(size_t)b * MAXBIN + pos] = ((unsigned int)(d & 255) << 24) | (unsigned int)s;
    }
}

// ---------------- binB: drain bin -> slot csr, all block-local ----------------
__global__ __launch_bounds__(256) void binB_kernel(const unsigned int* __restrict__ ebin,
                                                   const int* __restrict__ gcnt,
                                                   int* __restrict__ cnt,
                                                   int* __restrict__ csr) {
    __shared__ int scnt[256];
    int b = blockIdx.x;
    int t = threadIdx.x;
    scnt[t] = 0;
    __syncthreads();
    int n0 = b << 8;
    int c = gcnt[b];
    const unsigned int* src = ebin + (size_t)b * MAXBIN;
    for (int i = t; i < c; i += 256) {
        unsigned int e = src[i];
        int dl = (int)(e >> 24);
        int slot = atomicAdd(&scnt[dl], 1);
        csr[(size_t)(n0 + dl) * CAP + slot] = (int)(e & 0xFFFFFFu);
    }
    __syncthreads();
    int node = n0 + t;
    if (node < N_NODES) cnt[node] = scnt[t];
}

// ---------------- gather (bf16): agg[n] = h[n] + sum_{s in N(n)} h[s] ----------------
__global__ __launch_bounds__(256) void gather_kernel(const unsigned short* __restrict__ h,
                                                     const int* __restrict__ cnt,
                                                     const int* __restrict__ csr,
                                                     unsigned short* __restrict__ agg) {
    int t = threadIdx.x;
    int node = blockIdx.x * 16 + (t >> 4);
    int q = t & 15;
    if (node >= N_NODES) return;
    const int* nl = csr + (size_t)node * CAP;
    int deg = cnt[node];
    float acc[8] = {0.f, 0.f, 0.f, 0.f, 0.f, 0.f, 0.f, 0.f};
    addrow(acc, *(const uint4*)(h + (size_t)node * HID + q * 8));
    int e = 0;
    for (; e + 8 <= deg; e += 8) {
        int s0 = nl[e], s1 = nl[e + 1], s2 = nl[e + 2], s3 = nl[e + 3];
        int s4 = nl[e + 4], s5 = nl[e + 5], s6 = nl[e + 6], s7 = nl[e + 7];
        uint4 w0 = *(const uint4*)(h + (size_t)s0 * HID + q * 8);
        uint4 w1 = *(const uint4*)(h + (size_t)s1 * HID + q * 8);
        uint4 w2 = *(const uint4*)(h + (size_t)s2 * HID + q * 8);
        uint4 w3 = *(const uint4*)(h + (size_t)s3 * HID + q * 8);
        uint4 w4 = *(const uint4*)(h + (size_t)s4 * HID + q * 8);
        uint4 w5 = *(const uint4*)(h + (size_t)s5 * HID + q * 8);
        uint4 w6 = *(const uint4*)(h + (size_t)s6 * HID + q * 8);
        uint4 w7 = *(const uint4*)(h + (size_t)s7 * HID + q * 8);
        addrow(acc, w0); addrow(acc, w1); addrow(acc, w2); addrow(acc, w3);
        addrow(acc, w4); addrow(acc, w5); addrow(acc, w6); addrow(acc, w7);
    }
    for (; e + 4 <= deg; e += 4) {
        int s0 = nl[e], s1 = nl[e + 1], s2 = nl[e + 2], s3 = nl[e + 3];
        uint4 w0 = *(const uint4*)(h + (size_t)s0 * HID + q * 8);
        uint4 w1 = *(const uint4*)(h + (size_t)s1 * HID + q * 8);
        uint4 w2 = *(const uint4*)(h + (size_t)s2 * HID + q * 8);
        uint4 w3 = *(const uint4*)(h + (size_t)s3 * HID + q * 8);
        addrow(acc, w0); addrow(acc, w1); addrow(acc, w2); addrow(acc, w3);
    }
    for (; e < deg; ++e) {
        addrow(acc, *(const uint4*)(h + (size_t)nl[e] * HID + q * 8));
    }
    uint4 o;
    o.x = pack2(acc[0], acc[1]);
    o.y = pack2(acc[2], acc[3]);
    o.z = pack2(acc[4], acc[5]);
    o.w = pack2(acc[6], acc[7]);
    *(uint4*)(agg + (size_t)node * HID + q * 8) = o;
}

// ---------------- MFMA MLP (round-5 proven LDS-staged core) + optional fused pool ----------------
// If gpool != nullptr: instead of storing the out tile, segment-sum it into
// gpool (batch sorted; per-thread serial scan over a 32-row half, flush on
// graph change). Last layer's 25.6 MB store+reload is eliminated.
__global__ __launch_bounds__(256) void mlp_kernel(const unsigned short* __restrict__ A,
                                                  const unsigned short* __restrict__ W1t,
                                                  const float* __restrict__ b1,
                                                  const unsigned short* __restrict__ W2t,
                                                  const float* __restrict__ b2,
                                                  unsigned short* __restrict__ out,
                                                  const int* __restrict__ batch,
                                                  float* __restrict__ gpool) {
    __shared__ unsigned short sA[64][136];  // row stride 272B = 17*16B
    __shared__ unsigned short sW[128][40];  // row stride 80B = 5*16B
    __shared__ float sb[128];
    __shared__ int sbatch[64];
    const int t = threadIdx.x;
    const int w = t >> 6;
    const int l = t & 63;
    const int lm = l & 15;
    const int quad = l >> 4;
    const int row0 = blockIdx.x * 64;

    for (int idx = t; idx < 1024; idx += 256) {
        int r = idx >> 4, c = idx & 15;
        int grow = row0 + r;
        uint4 v = make_uint4(0u, 0u, 0u, 0u);
        if (grow < N_NODES) v = *(const uint4*)(A + (size_t)grow * HID + c * 8);
        *(uint4*)&sA[r][c * 8] = v;
    }
    if (gpool && t < 64) {
        int n = row0 + t;
        sbatch[t] = (n < N_NODES) ? batch[n] : -1;
    }

    const unsigned short* Wt[2] = {W1t, W2t};
    const float* bias[2] = {b1, b2};

    for (int p = 0; p < 2; ++p) {
        if (t < 128) sb[t] = bias[p][t];
        f32x4 acc[8];
#pragma unroll
        for (int nt = 0; nt < 8; ++nt) acc[nt] = (f32x4){0.f, 0.f, 0.f, 0.f};

        for (int kc = 0; kc < 4; ++kc) {
            __syncthreads();   // first iteration also covers A-tile + sbatch loads
            for (int idx = t; idx < 512; idx += 256) {
                int n = idx >> 2, kq = idx & 3;
                *(uint4*)&sW[n][kq * 8] =
                    *(const uint4*)(Wt[p] + (size_t)n * HID + kc * 32 + kq * 8);
            }
            __syncthreads();
            bf16x8 a = *(const bf16x8*)&sA[w * 16 + lm][kc * 32 + quad * 8];
#pragma unroll
            for (int nt = 0; nt < 8; ++nt) {
                bf16x8 b = *(const bf16x8*)&sW[nt * 16 + lm][quad * 8];
                acc[nt] = __builtin_amdgcn_mfma_f32_16x16x32_bf16(a, b, acc[nt], 0, 0, 0);
            }
        }
        __syncthreads();
#pragma unroll
        for (int nt = 0; nt < 8; ++nt) {
            float bv = sb[nt * 16 + lm];
#pragma unroll
            for (int r = 0; r < 4; ++r) {
                int m = w * 16 + quad * 4 + r;
                float val = fmaxf(acc[nt][r] + bv, 0.f);
                sA[m][nt * 16 + lm] = f2bf(val);
            }
        }
        __syncthreads();
    }

    if (!gpool) {
        for (int idx = t; idx < 1024; idx += 256) {
            int r = idx >> 4, c = idx & 15;
            int grow = row0 + r;
            if (grow < N_NODES)
                *(uint4*)(out + (size_t)grow * HID + c * 8) = *(const uint4*)&sA[r][c * 8];
        }
    } else {
        // fused global_add_pool: thread t covers channel (t&127), rows [(t>>7)*32, +32)
        int c = t & 127;
        int r0 = (t >> 7) * 32;
        float acc = 0.f;
        int cur = sbatch[r0];
        for (int r = r0; r < r0 + 32; ++r) {
            int b = sbatch[r];
            if (b < 0) break;
            if (b != cur) {
                atomicAdd(&gpool[(size_t)cur * HID + c], acc);
                acc = 0.f;
                cur = b;
            }
            acc += bf2f(sA[r][c]);
        }
        if (cur >= 0) atomicAdd(&gpool[(size_t)cur * HID + c], acc);
    }
}

// ---------------- heads ----------------
__global__ __launch_bounds__(128) void head_kernel(const float* __restrict__ g,
                                                   const float* __restrict__ Wmu,
                                                   const float* __restrict__ bmu,
                                                   const float* __restrict__ Wlv,
                                                   const float* __restrict__ blv,
                                                   float* __restrict__ out) {
    __shared__ float sg[HID];
    int gi = blockIdx.x;
    sg[threadIdx.x] = g[(size_t)gi * HID + threadIdx.x];
    __syncthreads();
    int j = threadIdx.x & 63;
    bool is_lv = threadIdx.x >= 64;
    const float* W = is_lv ? Wlv : Wmu;
    float acc = is_lv ? blv[j] : bmu[j];
    for (int k = 0; k < HID; ++k) acc = fmaf(sg[k], W[k * LAT + j], acc);
    out[(is_lv ? (size_t)N_GRAPHS * LAT : 0) + (size_t)gi * LAT + j] = acc;
}

extern "C" void kernel_launch(void* const* d_in, const int* in_sizes, int n_in,
                              void* d_out, int out_size, void* d_ws, size_t ws_size,
                              hipStream_t stream) {
    const float* x     = (const float*)d_in[0];
    const int*   ei    = (const int*)d_in[1];
    const int*   batch = (const int*)d_in[2];
    const float* W1    = (const float*)d_in[3];
    const float* b1    = (const float*)d_in[4];
    const float* W2    = (const float*)d_in[5];
    const float* b2    = (const float*)d_in[6];
    const float* Wmu   = (const float*)d_in[7];
    const float* bmu   = (const float*)d_in[8];
    const float* Wlv   = (const float*)d_in[9];
    const float* blv   = (const float*)d_in[10];
    float* out = (float*)d_out;

    // g and gcnt adjacent -> single memset clears both
    float* g  = (float*)d_ws;                                      // 512 KB
    int* gcnt = (int*)(g + (size_t)N_GRAPHS * HID);                // 1.6 KB
    unsigned short* xb   = (unsigned short*)(gcnt + NBIN + 1);
    unsigned short* agg  = xb + (size_t)N_NODES * HID;             // 25.6 MB each
    unsigned short* hbuf = agg + (size_t)N_NODES * HID;
    unsigned short* Wt   = hbuf + (size_t)N_NODES * HID;           // 192 KB
    int* cnt = (int*)(Wt + (size_t)6 * HID * HID);                 // 400 KB
    int* csr = cnt + N_NODES;                                      // 25.6 MB
    unsigned int* ebin = (unsigned int*)(csr + (size_t)N_NODES * CAP);  // 7.2 MB

    hipMemsetAsync(g, 0, (size_t)N_GRAPHS * HID * sizeof(float) + (NBIN + 1) * sizeof(int),
                   stream);

    // ---- CSR build: LDS-binned two-phase ----
    binA_kernel<<<ABLOCKS, 256, 0, stream>>>(ei, gcnt, ebin);
    binB_kernel<<<NBIN, 256, 0, stream>>>(ebin, gcnt, cnt, csr);

    // ---- prep bf16 (fused x + W) ----
    prep_kernel<<<CVT_BLOCKS + 6, 256, 0, stream>>>(x, xb, W1, W2, Wt);

    const unsigned short* hcur = xb;
    for (int i = 0; i < N_LAYERS; ++i) {
        bool last = (i == N_LAYERS - 1);
        gather_kernel<<<(N_NODES + 15) / 16, 256, 0, stream>>>(hcur, cnt, csr, agg);
        mlp_kernel<<<(N_NODES + 63) / 64, 256, 0, stream>>>(
            agg, Wt + (size_t)(2 * i) * HID * HID, b1 + (size_t)i * HID,
            Wt + (size_t)(2 * i + 1) * HID * HID, b2 + (size_t)i * HID, hbuf,
            batch, last ? g : nullptr);
        hcur = hbuf;
    }
    head_kernel<<<N_GRAPHS, 128, 0, stream>>>(g, Wmu, bmu, Wlv, blv, out);
}

// Round 14
// 420.864 us; speedup vs baseline: 1.3447x; 1.1662x over previous
//
#include <hip/hip_runtime.h>

#define N_NODES 100000
#define N_EDGES 1600000
#define HID 128
#define LAT 64
#define N_LAYERS 3
#define N_GRAPHS 1000
#define CAP 64                                    // slots per node (P(deg>=64)~1e-19)
#define NBIN 391                                  // dst bins of 256 nodes (d >> 8)
#define MAXBIN 4608                               // bin capacity: mean 4096 + 8*sigma
#define ACHUNK 8192
#define ABLOCKS ((N_EDGES + ACHUNK - 1) / ACHUNK) // 196
#define CVT_BLOCKS (N_NODES * HID / 4 / 256)      // 12500

typedef short bf16x8 __attribute__((ext_vector_type(8)));
typedef float f32x4 __attribute__((ext_vector_type(4)));

__device__ __forceinline__ float bf2f(unsigned short h) {
    union { unsigned int u; float f; } c;
    c.u = ((unsigned int)h) << 16;
    return c.f;
}
__device__ __forceinline__ unsigned short f2bf(float f) {
    union { float f; unsigned int u; } c;
    c.f = f;
    unsigned int u = c.u;
    return (unsigned short)((u + 0x7fffu + ((u >> 16) & 1u)) >> 16);
}
__device__ __forceinline__ unsigned int pack2(float a, float b) {
    return (unsigned int)f2bf(a) | ((unsigned int)f2bf(b) << 16);
}
__device__ __forceinline__ void addrow(float* acc, uint4 w) {
    acc[0] += bf2f((unsigned short)w.x); acc[1] += bf2f((unsigned short)(w.x >> 16));
    acc[2] += bf2f((unsigned short)w.y); acc[3] += bf2f((unsigned short)(w.y >> 16));
    acc[4] += bf2f((unsigned short)w.z); acc[5] += bf2f((unsigned short)(w.z >> 16));
    acc[6] += bf2f((unsigned short)w.w); acc[7] += bf2f((unsigned short)(w.w >> 16));
}

// ---------------- prep: fused x fp32->bf16 + W transpose->bf16 ----------------
__global__ __launch_bounds__(256) void prep_kernel(const float* __restrict__ x,
                                                   unsigned short* __restrict__ xb,
                                                   const float* __restrict__ W1,
                                                   const float* __restrict__ W2,
                                                   unsigned short* __restrict__ Wt) {
    int blk = blockIdx.x;
    if (blk < 6) {
        const float* W = ((blk & 1) ? W2 : W1) + (size_t)(blk >> 1) * HID * HID;
        unsigned short* D = Wt + (size_t)blk * HID * HID;
        for (int idx = threadIdx.x; idx < HID * HID; idx += 256) {
            int n = idx >> 7, k = idx & 127;
            D[n * HID + k] = f2bf(W[k * HID + n]);
        }
        return;
    }
    int i = (blk - 6) * 256 + threadIdx.x;
    if (i >= N_NODES * HID / 4) return;
    float4 v = ((const float4*)x)[i];
    ((uint2*)xb)[i] = make_uint2(pack2(v.x, v.y), pack2(v.z, v.w));
}

// ---------------- binA: edges -> per-bin dense runs, packed (dlocal<<24)|src ----------------
__global__ __launch_bounds__(256) void binA_kernel(const int* __restrict__ ei,
                                                   int* __restrict__ gcnt,
                                                   unsigned int* __restrict__ ebin) {
    __shared__ unsigned int scount[NBIN];
    __shared__ unsigned int sfill[NBIN];
    int t = threadIdx.x;
    int base = blockIdx.x * ACHUNK;
    int n = N_EDGES - base;
    if (n > ACHUNK) n = ACHUNK;
    for (int i = t; i < NBIN; i += 256) scount[i] = 0u;
    __syncthreads();
    for (int i = t; i < n; i += 256) {
        int d = ei[N_EDGES + base + i];
        atomicAdd(&scount[d >> 8], 1u);
    }
    __syncthreads();
    for (int b = t; b < NBIN; b += 256) {
        unsigned int c = scount[b];
        sfill[b] = c ? (unsigned int)atomicAdd(&gcnt[b], (int)c) : 0u;
    }
    __syncthreads();
    for (int i = t; i < n; i += 256) {
        int s = ei[base + i];
        int d = ei[N_EDGES + base + i];
        int b = d >> 8;
        unsigned int pos = atomicAdd(&sfill[b], 1u);
        ebin[(size_t)b * MAXBIN + pos] = ((unsigned int)(d & 255) << 24) | (unsigned int)s;
    }
}

// ---------------- binB: drain bin -> slot csr, all block-local ----------------
__global__ __launch_bounds__(256) void binB_kernel(const unsigned int* __restrict__ ebin,
                                                   const int* __restrict__ gcnt,
                                                   int* __restrict__ cnt,
                                                   int* __restrict__ csr) {
    __shared__ int scnt[256];
    int b = blockIdx.x;
    int t = threadIdx.x;
    scnt[t] = 0;
    __syncthreads();
    int n0 = b << 8;
    int c = gcnt[b];
    const unsigned int* src = ebin + (size_t)b * MAXBIN;
    for (int i = t; i < c; i += 256) {
        unsigned int e = src[i];
        int dl = (int)(e >> 24);
        int slot = atomicAdd(&scnt[dl], 1);
        csr[(size_t)(n0 + dl) * CAP + slot] = (int)(e & 0xFFFFFFu);
    }
    __syncthreads();
    int node = n0 + t;
    if (node < N_NODES) cnt[node] = scnt[t];
}

// ---------------- gather (bf16): agg[n] = h[n] + sum_{s in N(n)} h[s] ----------------
__global__ __launch_bounds__(256) void gather_kernel(const unsigned short* __restrict__ h,
                                                     const int* __restrict__ cnt,
                                                     const int* __restrict__ csr,
                                                     unsigned short* __restrict__ agg) {
    int t = threadIdx.x;
    int node = blockIdx.x * 16 + (t >> 4);
    int q = t & 15;
    if (node >= N_NODES) return;
    const int* nl = csr + (size_t)node * CAP;
    int deg = cnt[node];
    float acc[8] = {0.f, 0.f, 0.f, 0.f, 0.f, 0.f, 0.f, 0.f};
    addrow(acc, *(const uint4*)(h + (size_t)node * HID + q * 8));
    int e = 0;
    for (; e + 8 <= deg; e += 8) {
        int s0 = nl[e], s1 = nl[e + 1], s2 = nl[e + 2], s3 = nl[e + 3];
        int s4 = nl[e + 4], s5 = nl[e + 5], s6 = nl[e + 6], s7 = nl[e + 7];
        uint4 w0 = *(const uint4*)(h + (size_t)s0 * HID + q * 8);
        uint4 w1 = *(const uint4*)(h + (size_t)s1 * HID + q * 8);
        uint4 w2 = *(const uint4*)(h + (size_t)s2 * HID + q * 8);
        uint4 w3 = *(const uint4*)(h + (size_t)s3 * HID + q * 8);
        uint4 w4 = *(const uint4*)(h + (size_t)s4 * HID + q * 8);
        uint4 w5 = *(const uint4*)(h + (size_t)s5 * HID + q * 8);
        uint4 w6 = *(const uint4*)(h + (size_t)s6 * HID + q * 8);
        uint4 w7 = *(const uint4*)(h + (size_t)s7 * HID + q * 8);
        addrow(acc, w0); addrow(acc, w1); addrow(acc, w2); addrow(acc, w3);
        addrow(acc, w4); addrow(acc, w5); addrow(acc, w6); addrow(acc, w7);
    }
    for (; e + 4 <= deg; e += 4) {
        int s0 = nl[e], s1 = nl[e + 1], s2 = nl[e + 2], s3 = nl[e + 3];
        uint4 w0 = *(const uint4*)(h + (size_t)s0 * HID + q * 8);
        uint4 w1 = *(const uint4*)(h + (size_t)s1 * HID + q * 8);
        uint4 w2 = *(const uint4*)(h + (size_t)s2 * HID + q * 8);
        uint4 w3 = *(const uint4*)(h + (size_t)s3 * HID + q * 8);
        addrow(acc, w0); addrow(acc, w1); addrow(acc, w2); addrow(acc, w3);
    }
    for (; e < deg; ++e) {
        addrow(acc, *(const uint4*)(h + (size_t)nl[e] * HID + q * 8));
    }
    uint4 o;
    o.x = pack2(acc[0], acc[1]);
    o.y = pack2(acc[2], acc[3]);
    o.z = pack2(acc[4], acc[5]);
    o.w = pack2(acc[6], acc[7]);
    *(uint4*)(agg + (size_t)node * HID + q * 8) = o;
}

// ---------------- MFMA MLP (round-5 proven LDS-staged core) + optional fused pool ----------------
__global__ __launch_bounds__(256) void mlp_kernel(const unsigned short* __restrict__ A,
                                                  const unsigned short* __restrict__ W1t,
                                                  const float* __restrict__ b1,
                                                  const unsigned short* __restrict__ W2t,
                                                  const float* __restrict__ b2,
                                                  unsigned short* __restrict__ out,
                                                  const int* __restrict__ batch,
                                                  float* __restrict__ gpool) {
    __shared__ unsigned short sA[64][136];  // row stride 272B = 17*16B
    __shared__ unsigned short sW[128][40];  // row stride 80B = 5*16B
    __shared__ float sb[128];
    __shared__ int sbatch[64];
    const int t = threadIdx.x;
    const int w = t >> 6;
    const int l = t & 63;
    const int lm = l & 15;
    const int quad = l >> 4;
    const int row0 = blockIdx.x * 64;

    for (int idx = t; idx < 1024; idx += 256) {
        int r = idx >> 4, c = idx & 15;
        int grow = row0 + r;
        uint4 v = make_uint4(0u, 0u, 0u, 0u);
        if (grow < N_NODES) v = *(const uint4*)(A + (size_t)grow * HID + c * 8);
        *(uint4*)&sA[r][c * 8] = v;
    }
    if (gpool && t < 64) {
        int n = row0 + t;
        sbatch[t] = (n < N_NODES) ? batch[n] : -1;
    }

    const unsigned short* Wt[2] = {W1t, W2t};
    const float* bias[2] = {b1, b2};

    for (int p = 0; p < 2; ++p) {
        if (t < 128) sb[t] = bias[p][t];
        f32x4 acc[8];
#pragma unroll
        for (int nt = 0; nt < 8; ++nt) acc[nt] = (f32x4){0.f, 0.f, 0.f, 0.f};

        for (int kc = 0; kc < 4; ++kc) {
            __syncthreads();   // first iteration also covers A-tile + sbatch loads
            for (int idx = t; idx < 512; idx += 256) {
                int n = idx >> 2, kq = idx & 3;
                *(uint4*)&sW[n][kq * 8] =
                    *(const uint4*)(Wt[p] + (size_t)n * HID + kc * 32 + kq * 8);
            }
            __syncthreads();
            bf16x8 a = *(const bf16x8*)&sA[w * 16 + lm][kc * 32 + quad * 8];
#pragma unroll
            for (int nt = 0; nt < 8; ++nt) {
                bf16x8 b = *(const bf16x8*)&sW[nt * 16 + lm][quad * 8];
                acc[nt] = __builtin_amdgcn_mfma_f32_16x16x32_bf16(a, b, acc[nt], 0, 0, 0);
            }
        }
        __syncthreads();
#pragma unroll
        for (int nt = 0; nt < 8; ++nt) {
            float bv = sb[nt * 16 + lm];
#pragma unroll
            for (int r = 0; r < 4; ++r) {
                int m = w * 16 + quad * 4 + r;
                float val = fmaxf(acc[nt][r] + bv, 0.f);
                sA[m][nt * 16 + lm] = f2bf(val);
            }
        }
        __syncthreads();
    }

    if (!gpool) {
        for (int idx = t; idx < 1024; idx += 256) {
            int r = idx >> 4, c = idx & 15;
            int grow = row0 + r;
            if (grow < N_NODES)
                *(uint4*)(out + (size_t)grow * HID + c * 8) = *(const uint4*)&sA[r][c * 8];
        }
    } else {
        // fused global_add_pool: thread t covers channel (t&127), rows [(t>>7)*32, +32)
        int c = t & 127;
        int r0 = (t >> 7) * 32;
        float acc = 0.f;
        int cur = sbatch[r0];
        for (int r = r0; r < r0 + 32; ++r) {
            int b = sbatch[r];
            if (b < 0) break;
            if (b != cur) {
                atomicAdd(&gpool[(size_t)cur * HID + c], acc);
                acc = 0.f;
                cur = b;
            }
            acc += bf2f(sA[r][c]);
        }
        if (cur >= 0) atomicAdd(&gpool[(size_t)cur * HID + c], acc);
    }
}

// ---------------- heads ----------------
__global__ __launch_bounds__(128) void head_kernel(const float* __restrict__ g,
                                                   const float* __restrict__ Wmu,
                                                   const float* __restrict__ bmu,
                                                   const float* __restrict__ Wlv,
                                                   const float* __restrict__ blv,
                                                   float* __restrict__ out) {
    __shared__ float sg[HID];
    int gi = blockIdx.x;
    sg[threadIdx.x] = g[(size_t)gi * HID + threadIdx.x];
    __syncthreads();
    int j = threadIdx.x & 63;
    bool is_lv = threadIdx.x >= 64;
    const float* W = is_lv ? Wlv : Wmu;
    float acc = is_lv ? blv[j] : bmu[j];
    for (int k = 0; k < HID; ++k) acc = fmaf(sg[k], W[k * LAT + j], acc);
    out[(is_lv ? (size_t)N_GRAPHS * LAT : 0) + (size_t)gi * LAT + j] = acc;
}

extern "C" void kernel_launch(void* const* d_in, const int* in_sizes, int n_in,
                              void* d_out, int out_size, void* d_ws, size_t ws_size,
                              hipStream_t stream) {
    const float* x     = (const float*)d_in[0];
    const int*   ei    = (const int*)d_in[1];
    const int*   batch = (const int*)d_in[2];
    const float* W1    = (const float*)d_in[3];
    const float* b1    = (const float*)d_in[4];
    const float* W2    = (const float*)d_in[5];
    const float* b2    = (const float*)d_in[6];
    const float* Wmu   = (const float*)d_in[7];
    const float* bmu   = (const float*)d_in[8];
    const float* Wlv   = (const float*)d_in[9];
    const float* blv   = (const float*)d_in[10];
    float* out = (float*)d_out;

    // 256B-aligned layout: all row-addressed buffers first (every size is a
    // multiple of 256B), small int arrays last. (R13 lesson: a 1568B offset
    // made every 256B row span 5 lines instead of 4 -> +43% gather FETCH.)
    unsigned short* xb   = (unsigned short*)d_ws;                  // 25.6 MB
    unsigned short* agg  = xb + (size_t)N_NODES * HID;             // 25.6 MB
    unsigned short* hbuf = agg + (size_t)N_NODES * HID;            // 25.6 MB
    int* csr = (int*)(hbuf + (size_t)N_NODES * HID);               // 25.6 MB
    unsigned int* ebin = (unsigned int*)(csr + (size_t)N_NODES * CAP);  // 7,206,912 B
    unsigned short* Wt = (unsigned short*)(ebin + (size_t)NBIN * MAXBIN); // 196,608 B
    float* g  = (float*)(Wt + (size_t)6 * HID * HID);              // 512,000 B
    int* gcnt = (int*)(g + (size_t)N_GRAPHS * HID);                // adjacent to g
    int* cnt  = gcnt + NBIN + 1;

    hipMemsetAsync(g, 0, (size_t)N_GRAPHS * HID * sizeof(float) + (NBIN + 1) * sizeof(int),
                   stream);

    // ---- CSR build: LDS-binned two-phase ----
    binA_kernel<<<ABLOCKS, 256, 0, stream>>>(ei, gcnt, ebin);
    binB_kernel<<<NBIN, 256, 0, stream>>>(ebin, gcnt, cnt, csr);

    // ---- prep bf16 (fused x + W) ----
    prep_kernel<<<CVT_BLOCKS + 6, 256, 0, stream>>>(x, xb, W1, W2, Wt);

    const unsigned short* hcur = xb;
    for (int i = 0; i < N_LAYERS; ++i) {
        bool last = (i == N_LAYERS - 1);
        gather_kernel<<<(N_NODES + 15) / 16, 256, 0, stream>>>(hcur, cnt, csr, agg);
        mlp_kernel<<<(N_NODES + 63) / 64, 256, 0, stream>>>(
            agg, Wt + (size_t)(2 * i) * HID * HID, b1 + (size_t)i * HID,
            Wt + (size_t)(2 * i + 1) * HID * HID, b2 + (size_t)i * HID, hbuf,
            batch, last ? g : nullptr);
        hcur = hbuf;
    }
    head_kernel<<<N_GRAPHS, 128, 0, stream>>>(g, Wmu, bmu, Wlv, blv, out);
}